// Round 4
// baseline (36.534 us; speedup 1.0000x reference)
//
#include <hip/hip_runtime.h>
#include <hip/hip_bf16.h>

// Conv encoder, rate 1/2, constraint length 3, GEN_POLY = ("101", "111").
//   c0[t] = u[t] ^ u[t-2]
//   c1[t] = u[t] ^ u[t-1] ^ u[t-2]     (u[-1] = u[-2] = 0 per row)
// out[b, 2t] = c0, out[b, 2t+1] = c1;  flat out index = 2 * flat in index.
//
// Bits are 0.0f/1.0f; {0x00000000, 0x3F800000} is closed under XOR, so we XOR
// raw bit patterns (no int<->float converts).
//
// Per thread-iteration: one uint2 pair (u[2i], u[2i+1]).
//   - main load   in2[idx]          (8 B/lane, packed 512 B/instr)
//   - lookback    in2[idx-1]        (same cachelines shifted 8 B -> L1/L2 hit,
//                                    issues independently of the main load —
//                                    no shfl, no divergent branch)
//   - store       out4[idx]         (16 B/lane, packed 1 KB/instr)
// Row starts: K=2048 -> pair-index multiple of 1024; zero the lookback there
// (and clamp the address so global thread 0 never reads below the buffer).
//
// Grid-stride with 4096 blocks x 8 iters amortizes workgroup dispatch ramp
// (32768 tiny blocks cost ~7-13 us of CP dispatch at ~1-2 WG/cycle).

__global__ __launch_bounds__(256) void conv_enc_kernel(
    const uint2* __restrict__ in2, uint4* __restrict__ out4, int nPairs) {
    int stride = gridDim.x * blockDim.x;
    int idx = blockIdx.x * blockDim.x + threadIdx.x;

    #pragma unroll 2
    for (; idx < nPairs; idx += stride) {
        uint2 v = in2[idx];                         // u[2i], u[2i+1]
        bool rs = (idx & 1023) == 0;                // row start?
        uint2 w = in2[rs ? idx : idx - 1];          // u[2i-2], u[2i-1]
        unsigned int p2 = rs ? 0u : w.x;
        unsigned int p1 = rs ? 0u : w.y;

        uint4 o;
        o.x = v.x ^ p2;              // c0[t]   = u[t]   ^ u[t-2]
        o.y = o.x ^ p1;              // c1[t]   = u[t]   ^ u[t-1] ^ u[t-2]
        o.z = v.y ^ p1;              // c0[t+1] = u[t+1] ^ u[t-1]
        o.w = o.z ^ v.x;             // c1[t+1] = u[t+1] ^ u[t]   ^ u[t-1]

        out4[idx] = o;
    }
}

extern "C" void kernel_launch(void* const* d_in, const int* in_sizes, int n_in,
                              void* d_out, int out_size, void* d_ws, size_t ws_size,
                              hipStream_t stream) {
    const uint2* in2 = (const uint2*)d_in[0];
    uint4* out4 = (uint4*)d_out;

    int nPairs = in_sizes[0] / 2;                   // 8,388,608
    int block = 256;
    int grid = 4096;                                // 1,048,576 threads, 8 iters

    conv_enc_kernel<<<grid, block, 0, stream>>>(in2, out4, nPairs);
}